// Round 5
// baseline (369.868 us; speedup 1.0000x reference)
//
#include <hip/hip_runtime.h>
#include <hip/hip_bf16.h>

typedef __attribute__((ext_vector_type(8))) short short8;
typedef __attribute__((ext_vector_type(4))) float floatx4;

__device__ inline unsigned short f2bf(float f) {
    unsigned int u = __float_as_uint(f);
    u += 0x7fffu + ((u >> 16) & 1u);           // round-to-nearest-even
    return (unsigned short)(u >> 16);
}

__device__ inline unsigned int pk_bf16(float lo, float hi) {
    __hip_bfloat162 h = __float22bfloat162_rn(float2{lo, hi});
    unsigned int u;
    __builtin_memcpy(&u, &h, 4);
    return u;
}

// ---------------- merged cast fp32 -> bf16 (all 5 tensors, one launch) -----
// Wq is pre-scaled by scale*log2(e) so flash computes exp2(q.k) directly.
__global__ void cast_all_kernel(const float* __restrict__ x,
                                const float* __restrict__ wq,
                                const float* __restrict__ wk,
                                const float* __restrict__ wv,
                                const float* __restrict__ wo,
                                unsigned short* __restrict__ xb,
                                unsigned short* __restrict__ wqkb,
                                unsigned short* __restrict__ wvb,
                                unsigned short* __restrict__ wob) {
    const float C2 = 0.08838834764831845f * 1.4426950408889634f;
    int bid = blockIdx.x;
    const float* src;
    unsigned short* dst;
    int base;
    float sc = 1.0f;
    if (bid < 8192)       { src = x;  dst = xb;             base = bid; }
    else if (bid < 12288) { src = wq; dst = wqkb;           base = bid - 8192; sc = C2; }
    else if (bid < 14336) { src = wk; dst = wqkb + 4194304; base = bid - 12288; }
    else if (bid < 16384) { src = wv; dst = wvb;            base = bid - 14336; }
    else                  { src = wo; dst = wob;            base = bid - 16384; }
    int i = base * 256 + threadIdx.x;   // float4 units
    float4 v = ((const float4*)src)[i];
    ushort4 o;
    o.x = f2bf(v.x * sc); o.y = f2bf(v.y * sc);
    o.z = f2bf(v.z * sc); o.w = f2bf(v.w * sc);
    ((ushort4*)dst)[i] = o;
}

// ---------------- 3-slot deep-pipeline GEMM core (T2+T3+T4+T5) -------------
// C[m,n] = sum_k A[m,k]*B[n,k]; K=2048 fixed. Tile 128x256, BK=64, 512 thr
// (8 waves 2Mx4N, wave-out 64x64, acc 4x4 = proven fragment formulas).
// LDS: 3 slots x (A 128x64 + B 256x64), XOR-chunk swizzle (row R, k-chunk j
// at slot j^(R&7)). Tile t computed from slot t%3 while t+1,t+2 stream in:
// staging issued 2 tiles early -> per-tile wait is vmcnt(6) (in-order vmcnt:
// everything older than the newest 6 loads has landed). NO vmcnt(0) drain in
// the main loop; last tile peeled. Overwrite-safe: tile t+2 lands in t-1's
// slot, staged only after the tile-t barrier (all waves done reading t-1).
template <int OUT_BF16>
__device__ __forceinline__ void gemm256_body(
        const unsigned short* __restrict__ A,
        const unsigned short* __restrict__ B,
        void* __restrict__ Cp, int ldc, int m0, int n0,
        unsigned short* sAb, unsigned short* sBb) {
    const int tid  = threadIdx.x;
    const int wave = tid >> 6;
    const int lane = tid & 63;
    const int l16  = lane & 15;
    const int lq   = lane >> 4;
    const int wm   = (wave >> 2) * 64;
    const int wn   = (wave & 3) * 64;

    floatx4 acc[4][4] = {};

    // staging addrs: chunk c covers rows c*8..c*8+7 (64 cols, 1KB, one
    // global_load_lds per wave). lane l -> row c*8+(l>>3), lds slot l&7,
    // global chunk (l&7)^(row&7).  A: 16 chunks (wave*2+i). B: 32 chunks in
    // 2 units of 16 (u*16 + wave*2 + i).
    const unsigned short* gA[2];
    const unsigned short* gB[4];
#pragma unroll
    for (int i = 0; i < 2; i++) {
        int c   = wave * 2 + i;
        int row = c * 8 + (lane >> 3);
        int chs = (lane & 7) ^ (row & 7);
        gA[i] = A + (size_t)(m0 + row) * 2048 + chs * 8;
    }
#pragma unroll
    for (int u = 0; u < 2; u++)
#pragma unroll
        for (int i = 0; i < 2; i++) {
            int c   = u * 16 + wave * 2 + i;
            int row = c * 8 + (lane >> 3);
            int chs = (lane & 7) ^ (row & 7);
            gB[u * 2 + i] = B + (size_t)(n0 + row) * 2048 + chs * 8;
        }

#define STG_A(slot)                                                            \
    do {                                                                       \
        _Pragma("unroll")                                                      \
        for (int i = 0; i < 2; i++) {                                          \
            __builtin_amdgcn_global_load_lds(                                  \
                (const __attribute__((address_space(1))) void*)gA[i],          \
                (__attribute__((address_space(3))) void*)(sAb + (slot) * 8192 +\
                                                          (wave * 2 + i) * 512),\
                16, 0, 0);                                                     \
            gA[i] += 64;                                                       \
        }                                                                      \
    } while (0)
#define STG_B(slot, u)                                                         \
    do {                                                                       \
        _Pragma("unroll")                                                      \
        for (int i = 0; i < 2; i++) {                                          \
            __builtin_amdgcn_global_load_lds(                                  \
                (const __attribute__((address_space(1))) void*)gB[(u) * 2 + i],\
                (__attribute__((address_space(3))) void*)(sBb + (slot) * 16384 \
                                                  + ((u) * 16 + wave * 2 + i) * 512),\
                16, 0, 0);                                                     \
            gB[(u) * 2 + i] += 64;                                             \
        }                                                                      \
    } while (0)

#define COMPUTE_KS(sA, sB, ks)                                                 \
    do {                                                                       \
        short8 af[4], bfr[4];                                                  \
        int slot = ((ks) * 4 + lq) ^ (l16 & 7);                                \
        _Pragma("unroll")                                                      \
        for (int mb = 0; mb < 4; mb++)                                         \
            af[mb] = *(const short8*)((sA) + (wm + mb * 16 + l16) * 64 +       \
                                      slot * 8);                               \
        _Pragma("unroll")                                                      \
        for (int nb = 0; nb < 4; nb++)                                         \
            bfr[nb] = *(const short8*)((sB) + (wn + nb * 16 + l16) * 64 +      \
                                       slot * 8);                              \
        __builtin_amdgcn_s_setprio(1);                                         \
        _Pragma("unroll")                                                      \
        for (int mb = 0; mb < 4; mb++)                                         \
            _Pragma("unroll")                                                  \
            for (int nb = 0; nb < 4; nb++)                                     \
                acc[mb][nb] = __builtin_amdgcn_mfma_f32_16x16x32_bf16(         \
                    af[mb], bfr[nb], acc[mb][nb], 0, 0, 0);                    \
        __builtin_amdgcn_s_setprio(0);                                         \
    } while (0)

    // prologue: stage tiles 0,1 into slots 0,1 (12 loads in flight)
    STG_A(0); STG_B(0, 0); STG_B(0, 1);
    STG_A(1); STG_B(1, 0); STG_B(1, 1);

    int sc = 0;                       // slot of tile t
    for (int t = 0; t < 31; t++) {
        int sn = sc + 2; if (sn >= 3) sn -= 3;    // slot for tile t+2
        asm volatile("s_waitcnt vmcnt(6)" ::: "memory");  // tile t fully landed
        __builtin_amdgcn_s_barrier();
        asm volatile("" ::: "memory");
        const unsigned short* sA = sAb + sc * 8192;
        const unsigned short* sB = sBb + sc * 16384;
        // phase 0: stage A + B0 of t+2, compute ks0
        if (t < 30) { STG_A(sn); STG_B(sn, 0); }
        COMPUTE_KS(sA, sB, 0);
        __builtin_amdgcn_s_barrier();
        asm volatile("" ::: "memory");
        // phase 1: stage B1 of t+2, compute ks1
        if (t < 30) STG_B(sn, 1);
        COMPUTE_KS(sA, sB, 1);
        sc = sc + 1; if (sc >= 3) sc -= 3;
    }
    // last tile (t=31): full drain
    asm volatile("s_waitcnt vmcnt(0)" ::: "memory");
    __builtin_amdgcn_s_barrier();
    asm volatile("" ::: "memory");
    {
        const unsigned short* sA = sAb + sc * 8192;
        const unsigned short* sB = sBb + sc * 16384;
        COMPUTE_KS(sA, sB, 0);
        COMPUTE_KS(sA, sB, 1);
    }
#undef STG_A
#undef STG_B
#undef COMPUTE_KS

#pragma unroll
    for (int mb = 0; mb < 4; mb++)
#pragma unroll
        for (int nb = 0; nb < 4; nb++)
#pragma unroll
            for (int r = 0; r < 4; r++) {
                int row = m0 + wm + mb * 16 + lq * 4 + r;
                int col = n0 + wn + nb * 16 + l16;
                if (OUT_BF16)
                    ((unsigned short*)Cp)[(size_t)row * ldc + col] = f2bf(acc[mb][nb][r]);
                else
                    ((float*)Cp)[(size_t)row * ldc + col] = acc[mb][nb][r];
            }
}

// ---------------- merged QK + Vt gemm (one dispatch, 512 blocks) -----------
__global__ __launch_bounds__(512, 1) void gemm_qkv_kernel(
        const unsigned short* __restrict__ x_bf,
        const unsigned short* __restrict__ Wqk,
        const unsigned short* __restrict__ Wv,
        unsigned short* __restrict__ QKb,
        unsigned short* __restrict__ Vtb) {
    __shared__ __align__(16) unsigned short sAb[3 * 8192];    // 48 KB
    __shared__ __align__(16) unsigned short sBb[3 * 16384];   // 96 KB
    const int bid = blockIdx.x;
    if (bid < 384) {
        // QK = x @ [Wq;Wk]^T : M=4096 N=3072 (tiles 32 x 12)
        gemm256_body<1>(x_bf, Wqk, QKb, 3072,
                        (bid / 12) * 128, (bid % 12) * 256, sAb, sBb);
    } else {
        // Vt = Wv @ x^T : M=1024 N=4096 (tiles 8 x 16)
        int t = bid - 384;
        gemm256_body<1>(Wv, x_bf, Vtb, 4096,
                        (t / 16) * 128, (t % 16) * 256, sAb, sBb);
    }
}

// ---------------- O-proj gemm (fp32 out, 256 blocks) ----------------
__global__ __launch_bounds__(512, 1) void gemm_o_kernel(
        const unsigned short* __restrict__ A,
        const unsigned short* __restrict__ B,
        float* __restrict__ C) {
    __shared__ __align__(16) unsigned short sAb[3 * 8192];
    __shared__ __align__(16) unsigned short sBb[3 * 16384];
    gemm256_body<0>(A, B, C, 2048,
                    blockIdx.y * 128, blockIdx.x * 256, sAb, sBb);
}

// ---------------- flash attention v4 (best measured: 100.3 us) -------------
// 4 waves = 4 q-slices (32 q-rows each); every wave covers ALL 64 keys/kt.
//  - per-wave state ~155 regs, below cap: no spill
//  - keys split into two 32-key PV steps: PV(ks0) emitted before QK(kb2,3)+SM
//  - sP wave-PRIVATE (4KB/wave): lgkmcnt-only sync
//  - double-buffered sK/sV (64KB) + sP (16KB) = 80KB -> 2 blocks/CU
__global__ __launch_bounds__(256, 2) void flash_kernel(
        const unsigned short* __restrict__ QK,
        const unsigned short* __restrict__ Vt,
        unsigned short* __restrict__ O) {
    // layout (ushorts): sK[2][8192] @0, sV[2][8192] @16384, sP[4][2048] @32768
    __shared__ __align__(16) unsigned short smem[40960];

    const int tid  = threadIdx.x;
    const int wave = tid >> 6;
    const int lane = tid & 63;
    const int l16  = lane & 15;
    const int lq   = lane >> 4;
    const int qt   = blockIdx.x;          // 0..15 (128 tokens each)
    const int bh   = blockIdx.y;
    const int b    = bh >> 4;
    const int h    = bh & 15;
    const int kvh  = h >> 1;
    const size_t tokbase = (size_t)b * 2048 + qt * 128 + wave * 32;

    // Q fragments: 32 rows x 128 d per wave (B-operand, col = q = l16)
    short8 qf[2][4];
#pragma unroll
    for (int qb = 0; qb < 2; qb++) {
        const unsigned short* qp =
            QK + (tokbase + qb * 16 + l16) * 3072 + h * 128 + lq * 8;
#pragma unroll
        for (int c = 0; c < 4; c++) qf[qb][c] = *(const short8*)(qp + c * 32);
    }

    // staging pointers: wave handles K segs / V segs {wave*4 .. wave*4+3}
    const unsigned short* gKe =
        QK + ((size_t)b * 2048 + wave * 16 + lq) * 3072 + 2048 + kvh * 128 +
        (l16 ^ lq) * 8;
    const unsigned short* gKo =
        QK + ((size_t)b * 2048 + wave * 16 + 4 + lq) * 3072 + 2048 + kvh * 128 +
        (l16 ^ (lq + 4)) * 8;
    const unsigned short* gV0 =
        Vt + (size_t)(kvh * 128 + wave * 32 + (lane >> 3)) * 4096 +
        (size_t)b * 2048 + ((lane & 7) ^ (lane >> 3)) * 8;

#define STAGE_KT(sKd, sVd)                                                     \
    do {                                                                       \
        _Pragma("unroll")                                                      \
        for (int i = 0; i < 4; i++) {                                          \
            const unsigned short* gk =                                         \
                ((i & 1) ? gKo : gKe) + (i >> 1) * 24576;                      \
            __builtin_amdgcn_global_load_lds(                                  \
                (const __attribute__((address_space(1))) void*)gk,             \
                (__attribute__((address_space(3))) void*)((sKd) +              \
                                                          (wave * 4 + i) * 512),\
                16, 0, 0);                                                     \
            __builtin_amdgcn_global_load_lds(                                  \
                (const __attribute__((address_space(1))) void*)(gV0 +          \
                                                               i * 32768),     \
                (__attribute__((address_space(3))) void*)((sVd) +              \
                                                          (wave * 4 + i) * 512),\
                16, 0, 0);                                                     \
        }                                                                      \
        gKe += 196608; gKo += 196608; gV0 += 64;                               \
    } while (0)

    // wave-private P region: 32 rows x 64 keys, XOR-chunk swizzled
    unsigned short* pB = smem + 32768 + wave * 2048;

    floatx4 oacc[2][8] = {};
    float l_run[2] = {0.0f, 0.0f};

    // prologue: stage tile 0, drain, barrier
    STAGE_KT(smem, smem + 16384);
    asm volatile("s_waitcnt vmcnt(0)" ::: "memory");
    __builtin_amdgcn_s_barrier();
    asm volatile("" ::: "memory");

    for (int kt = 0; kt < 32; kt++) {
        const int cur = kt & 1;
        const unsigned short* sKc = smem + cur * 8192;
        const unsigned short* sVc = smem + 16384 + cur * 8192;
        if (kt < 31) {
            unsigned short* sKn = smem + (cur ^ 1) * 8192;
            unsigned short* sVn = smem + 16384 + (cur ^ 1) * 8192;
            STAGE_KT(sKn, sVn);          // latency hides under this kt's compute
        }

        // ===== ks0: QK over kb=0,1 + softmax + P write (keys 0..31) =====
#pragma unroll
        for (int kb = 0; kb < 2; kb++) {
            floatx4 sacc[2] = {};
#pragma unroll
            for (int c = 0; c < 4; c++) {
                short8 kf = *(const short8*)(
                    sKc + (kb * 16 + l16) * 128 + (((c * 4 + lq) ^ (l16 & 7)) * 8));
#pragma unroll
                for (int qb = 0; qb < 2; qb++)
                    sacc[qb] = __builtin_amdgcn_mfma_f32_16x16x32_bf16(
                        kf, qf[qb][c], sacc[qb], 0, 0, 0);
            }
#pragma unroll
            for (int qb = 0; qb < 2; qb++) {
                float p0 = __builtin_exp2f(sacc[qb][0]);
                float p1 = __builtin_exp2f(sacc[qb][1]);
                float p2 = __builtin_exp2f(sacc[qb][2]);
                float p3 = __builtin_exp2f(sacc[qb][3]);
                l_run[qb] += (p0 + p1) + (p2 + p3);
                int row = qb * 16 + l16;
                uint2 u;
                u.x = pk_bf16(p0, p1);
                u.y = pk_bf16(p2, p3);
                *(uint2*)(pB + row * 64 +
                          (((kb * 2 + (lq >> 1)) ^ (row & 7)) * 8) +
                          (lq & 1) * 4) = u;
            }
        }
        asm volatile("s_waitcnt lgkmcnt(0)" ::: "memory");

        // P fragments ks0 (B-operand: col=q=l16, keys lq*8..+7)
        short8 pf0[2];
#pragma unroll
        for (int qb = 0; qb < 2; qb++) {
            int row = qb * 16 + l16;
            pf0[qb] = *(const short8*)(pB + row * 64 +
                                       ((lq ^ (row & 7)) * 8));
        }

        // ===== PV(ks0) =====
        __builtin_amdgcn_s_setprio(1);
#pragma unroll
        for (int nb = 0; nb < 8; nb++) {
            short8 vf = *(const short8*)(
                sVc + (nb * 16 + l16) * 64 + ((lq ^ (l16 & 7)) * 8));
#pragma unroll
            for (int qb = 0; qb < 2; qb++)
                oacc[qb][nb] = __builtin_amdgcn_mfma_f32_16x16x32_bf16(
                    vf, pf0[qb], oacc[qb][nb], 0, 0, 0);
        }
        __builtin_amdgcn_s_setprio(0);

        // ===== ks1: QK over kb=2,3 + softmax + P write (keys 32..63) =====
#pragma unroll
        for (int kb = 2; kb < 4; kb++) {
            floatx4 sacc[2] = {};
#pragma unroll
            for (int c = 0; c < 4; c++) {
                short8 kf = *(const short8*)(
                    sKc + (kb * 16 + l16) * 128 + (((c * 4 + lq) ^ (l16 & 7)) * 8));
#pragma unroll
                for (int qb = 0; qb < 2; qb++)
                    sacc[qb] = __builtin_amdgcn_mfma_f32_16x16x32_bf16(
                        kf, qf[qb][c], sacc[qb], 0, 0, 0);
            }
#pragma unroll
            for (int qb = 0; qb < 2; qb++) {
                float p0 = __builtin_exp2f(sacc[qb][0]);
                float p1 = __builtin_exp2f(sacc[qb][1]);
                float p2 = __builtin_exp2f(sacc[qb][2]);
                float p3 = __builtin_exp2f(sacc[qb][3]);
                l_run[qb] += (p0 + p1) + (p2 + p3);
                int row = qb * 16 + l16;
                uint2 u;
                u.x = pk_bf16(p0, p1);
                u.y = pk_bf16(p2, p3);
                *(uint2*)(pB + row * 64 +
                          (((kb * 2 + (lq >> 1)) ^ (row & 7)) * 8) +
                          (lq & 1) * 4) = u;
            }
        }
        asm volatile("s_waitcnt lgkmcnt(0)" ::: "memory");

        short8 pf1[2];
#pragma unroll
        for (int qb = 0; qb < 2; qb++) {
            int row = qb * 16 + l16;
            pf1[qb] = *(const short8*)(pB + row * 64 +
                                       (((4 + lq) ^ (row & 7)) * 8));
        }

        // ===== PV(ks1) =====
        __builtin_amdgcn_s_setprio(1);
#pragma unroll
        for (int nb = 0; nb < 8; nb++) {
            short8 vf = *(const short8*)(
                sVc + (nb * 16 + l16) * 64 + (((4 + lq) ^ (l16 & 7)) * 8));
#pragma unroll
            for (int qb = 0; qb < 2; qb++)
                oacc[qb][nb] = __builtin_amdgcn_mfma_f32_16x16x32_bf16(
                    vf, pf1[qb], oacc[qb][nb], 0, 0, 0);
        }
        __builtin_amdgcn_s_setprio(0);

        // end of phase: drain staging issued this kt, then barrier
        asm volatile("s_waitcnt vmcnt(0)" ::: "memory");
        __builtin_amdgcn_s_barrier();
        asm volatile("" ::: "memory");
    }
#undef STAGE_KT

    // ---- epilogue: wave owns full key range -> direct store ----
#pragma unroll
    for (int qb = 0; qb < 2; qb++) {
        float l = l_run[qb];
        l += __shfl_xor(l, 16);
        l += __shfl_xor(l, 32);
        float inv = 1.0f / l;
        size_t row = (tokbase + qb * 16 + l16) * 2048 + h * 128;
#pragma unroll
        for (int nb = 0; nb < 8; nb++) {
            uint2 u;
            u.x = pk_bf16(oacc[qb][nb][0] * inv, oacc[qb][nb][1] * inv);
            u.y = pk_bf16(oacc[qb][nb][2] * inv, oacc[qb][nb][3] * inv);
            *(uint2*)(O + row + nb * 16 + lq * 4) = u;
        }
    }
}

// ---------------- launcher ----------------
extern "C" void kernel_launch(void* const* d_in, const int* in_sizes, int n_in,
                              void* d_out, int out_size, void* d_ws, size_t ws_size,
                              hipStream_t stream) {
    const float* x  = (const float*)d_in[0];
    const float* Wq = (const float*)d_in[1];
    const float* Wk = (const float*)d_in[2];
    const float* Wv = (const float*)d_in[3];
    const float* Wo = (const float*)d_in[4];

    char* ws = (char*)d_ws;
    unsigned short* x_bf   = (unsigned short*)(ws);               // 16 MB
    unsigned short* Wqk_bf = (unsigned short*)(ws + 16777216);    // 12 MB (Wq;Wk)
    unsigned short* Wv_bf  = (unsigned short*)(ws + 29360128);    // 4 MB
    unsigned short* Wo_bf  = (unsigned short*)(ws + 33554432);    // 8 MB
    unsigned short* QKb    = (unsigned short*)(ws + 41943040);    // 24 MB (4096x3072)
    unsigned short* Vtb    = (unsigned short*)(ws + 67108864);    // 8 MB  (1024x4096)
    unsigned short* Ob     = (unsigned short*)(ws + 75497472);    // 16 MB (4096x2048)

    cast_all_kernel<<<dim3(20480), 256, 0, stream>>>(
        x, Wq, Wk, Wv, Wo, x_bf, Wqk_bf, Wv_bf, Wo_bf);

    // QK = x @ [Wq;Wk]^T  and  Vt = Wv @ x^T, merged (512 blocks, 512 thr)
    gemm_qkv_kernel<<<dim3(512), 512, 0, stream>>>(x_bf, Wqk_bf, Wv_bf, QKb, Vtb);

    // flash attention: 128 tokens/block
    flash_kernel<<<dim3(16, 32), 256, 0, stream>>>(QKb, Vtb, Ob);

    // out = O @ Wo^T : M=4096, N=2048, K=2048, fp32 out (tiles 32 x 8)
    gemm_o_kernel<<<dim3(8, 32), 512, 0, stream>>>(Ob, Wo_bf, (float*)d_out);
}

// Round 7
// 316.373 us; speedup vs baseline: 1.1691x; 1.1691x over previous
//
#include <hip/hip_runtime.h>
#include <hip/hip_bf16.h>

typedef __attribute__((ext_vector_type(8))) short short8;
typedef __attribute__((ext_vector_type(4))) float floatx4;

__device__ inline unsigned short f2bf(float f) {
    unsigned int u = __float_as_uint(f);
    u += 0x7fffu + ((u >> 16) & 1u);           // round-to-nearest-even
    return (unsigned short)(u >> 16);
}

__device__ inline unsigned int pk_bf16(float lo, float hi) {
    __hip_bfloat162 h = __float22bfloat162_rn(float2{lo, hi});
    unsigned int u;
    __builtin_memcpy(&u, &h, 4);
    return u;
}

// ---------------- merged cast fp32 -> bf16 (all 5 tensors, one launch) -----
// Wq is pre-scaled by scale*log2(e) so flash computes exp2(q.k) directly.
__global__ void cast_all_kernel(const float* __restrict__ x,
                                const float* __restrict__ wq,
                                const float* __restrict__ wk,
                                const float* __restrict__ wv,
                                const float* __restrict__ wo,
                                unsigned short* __restrict__ xb,
                                unsigned short* __restrict__ wqkb,
                                unsigned short* __restrict__ wvb,
                                unsigned short* __restrict__ wob) {
    const float C2 = 0.08838834764831845f * 1.4426950408889634f;
    int bid = blockIdx.x;
    const float* src;
    unsigned short* dst;
    int base;
    float sc = 1.0f;
    if (bid < 8192)       { src = x;  dst = xb;             base = bid; }
    else if (bid < 12288) { src = wq; dst = wqkb;           base = bid - 8192; sc = C2; }
    else if (bid < 14336) { src = wk; dst = wqkb + 4194304; base = bid - 12288; }
    else if (bid < 16384) { src = wv; dst = wvb;            base = bid - 14336; }
    else                  { src = wo; dst = wob;            base = bid - 16384; }
    int i = base * 256 + threadIdx.x;   // float4 units
    float4 v = ((const float4*)src)[i];
    ushort4 o;
    o.x = f2bf(v.x * sc); o.y = f2bf(v.y * sc);
    o.z = f2bf(v.z * sc); o.w = f2bf(v.w * sc);
    ((ushort4*)dst)[i] = o;
}

// ---------------- 256x256 8-phase GEMM, race-hardened pipeline -------------
// C[m,n] = sum_k A[m,k]*B[n,k]; K=2048 (64 K-tiles of 32). 512 thr, 8 waves
// (2M x 4N), wave-out 128x64, acc[8][4]. LDS: 4 slots x (A 256x32 + B 256x32)
// = 128 KB.
// PIPELINE (hardened vs r6 which raced): stage runs TWO K-tiles ahead.
// Iter t: read slot t&3; tile t+1 in flight; stage tile t+2 into slot
// (t+2)&3 = slot of tile t-2, whose reads retired before TWO top barriers
// (double slack: safe even if one barrier-ordering link leaks).
// Boundary wait = counted vmcnt(4): 8 loads outstanding (tiles t,t+1),
// retire tile t's 4, keep t+1 in flight across the barrier (T4). Extra
// compiler vmem ops only strengthen the wait (vmcnt(N) with more
// outstanding retires more), never weaken it.
// Per tile: 2 phases, each {ds_read || stage -> barrier -> lgkmcnt(0) ->
// sched_barrier(0) -> setprio(1) -> 16 MFMA -> setprio(0) -> barrier}.
// Chunk = 16 rows x 32 cols (1KB): lane l -> row c*16+(l>>2), lds k-slot l&3
// holds global k-chunk (l&3)^(row&3); frag read slot = lq^(l16&3).
template <int OUT_BF16>
__device__ __forceinline__ void gemm256_body(
        const unsigned short* __restrict__ A,
        const unsigned short* __restrict__ B,
        void* __restrict__ Cp, int ldc, int m0, int n0,
        unsigned short* sL) {
    const int tid  = threadIdx.x;
    const int wave = tid >> 6;
    const int lane = tid & 63;
    const int l16  = lane & 15;
    const int lq   = lane >> 4;
    const int wm   = (wave >> 2) * 128;
    const int wn   = (wave & 3) * 64;
    const int kx   = lq ^ (l16 & 3);

    floatx4 acc[8][4] = {};

    const unsigned short* gA[2];
    const unsigned short* gB[2];
#pragma unroll
    for (int i = 0; i < 2; i++) {
        int c   = wave * 2 + i;
        int row = c * 16 + (lane >> 2);
        int g   = (lane & 3) ^ (row & 3);
        gA[i] = A + (size_t)(m0 + row) * 2048 + g * 8;
        gB[i] = B + (size_t)(n0 + row) * 2048 + g * 8;
    }

#define STG_A32(slot)                                                          \
    do {                                                                       \
        _Pragma("unroll")                                                      \
        for (int i = 0; i < 2; i++) {                                          \
            __builtin_amdgcn_global_load_lds(                                  \
                (const __attribute__((address_space(1))) void*)gA[i],          \
                (__attribute__((address_space(3))) void*)(sL + (slot) * 16384 +\
                                                          (wave * 2 + i) * 512),\
                16, 0, 0);                                                     \
            gA[i] += 32;                                                       \
        }                                                                      \
    } while (0)
#define STG_B32(slot)                                                          \
    do {                                                                       \
        _Pragma("unroll")                                                      \
        for (int i = 0; i < 2; i++) {                                          \
            __builtin_amdgcn_global_load_lds(                                  \
                (const __attribute__((address_space(1))) void*)gB[i],          \
                (__attribute__((address_space(3))) void*)(sL + (slot) * 16384 +\
                                                  8192 + (wave * 2 + i) * 512),\
                16, 0, 0);                                                     \
            gB[i] += 32;                                                       \
        }                                                                      \
    } while (0)

    // prologue: stage tiles 0,1 into slots 0,1 (8 loads/wave in flight)
    STG_A32(0); STG_B32(0);
    STG_A32(1); STG_B32(1);

    for (int t = 0; t < 64; t++) {
        const int sc = t & 3;
        const int sn = (t + 2) & 3;        // slot of tile t-2 (retired reads)
        // boundary: retire tile t's 4 loads; tile t+1 stays in flight
        if (t < 63) asm volatile("s_waitcnt vmcnt(4)" ::: "memory");
        else        asm volatile("s_waitcnt vmcnt(0)" ::: "memory");
        __builtin_amdgcn_s_barrier();
        asm volatile("" ::: "memory");

        const unsigned short* sAc = sL + sc * 16384;
        const unsigned short* sBc = sAc + 8192;
        short8 af[4], bf[4];

        // ---- phase 0: mh0 (mb 0-3) ----
#pragma unroll
        for (int mb = 0; mb < 4; mb++)
            af[mb] = *(const short8*)(sAc + (wm + mb * 16 + l16) * 32 + kx * 8);
#pragma unroll
        for (int nb = 0; nb < 4; nb++)
            bf[nb] = *(const short8*)(sBc + (wn + nb * 16 + l16) * 32 + kx * 8);
        if (t < 62) STG_A32(sn);
        __builtin_amdgcn_s_barrier();
        asm volatile("s_waitcnt lgkmcnt(0)" ::: "memory");
        __builtin_amdgcn_sched_barrier(0);
        __builtin_amdgcn_s_setprio(1);
#pragma unroll
        for (int mb = 0; mb < 4; mb++)
#pragma unroll
            for (int nb = 0; nb < 4; nb++)
                acc[mb][nb] = __builtin_amdgcn_mfma_f32_16x16x32_bf16(
                    af[mb], bf[nb], acc[mb][nb], 0, 0, 0);
        __builtin_amdgcn_s_setprio(0);
        __builtin_amdgcn_s_barrier();
        asm volatile("" ::: "memory");

        // ---- phase 1: mh1 (mb 4-7), bf reused from registers ----
#pragma unroll
        for (int mb = 0; mb < 4; mb++)
            af[mb] = *(const short8*)(sAc + (wm + 64 + mb * 16 + l16) * 32 + kx * 8);
        if (t < 62) STG_B32(sn);
        __builtin_amdgcn_s_barrier();
        asm volatile("s_waitcnt lgkmcnt(0)" ::: "memory");
        __builtin_amdgcn_sched_barrier(0);
        __builtin_amdgcn_s_setprio(1);
#pragma unroll
        for (int mb = 0; mb < 4; mb++)
#pragma unroll
            for (int nb = 0; nb < 4; nb++)
                acc[4 + mb][nb] = __builtin_amdgcn_mfma_f32_16x16x32_bf16(
                    af[mb], bf[nb], acc[4 + mb][nb], 0, 0, 0);
        __builtin_amdgcn_s_setprio(0);
        // tile closed by next iteration's vmcnt + barrier
    }
#undef STG_A32
#undef STG_B32

#pragma unroll
    for (int mb = 0; mb < 8; mb++)
#pragma unroll
        for (int nb = 0; nb < 4; nb++)
#pragma unroll
            for (int r = 0; r < 4; r++) {
                int row = m0 + wm + mb * 16 + lq * 4 + r;
                int col = n0 + wn + nb * 16 + l16;
                if (OUT_BF16)
                    ((unsigned short*)Cp)[(size_t)row * ldc + col] = f2bf(acc[mb][nb][r]);
                else
                    ((float*)Cp)[(size_t)row * ldc + col] = acc[mb][nb][r];
            }
}

// ---------------- merged QK + Vt gemm (256 blocks = 1/CU) ------------------
__global__ __launch_bounds__(512, 1) void gemm_qkv_kernel(
        const unsigned short* __restrict__ x_bf,
        const unsigned short* __restrict__ Wqk,
        const unsigned short* __restrict__ Wv,
        unsigned short* __restrict__ QKb,
        unsigned short* __restrict__ Vtb) {
    __shared__ __align__(16) unsigned short sL[4 * 16384];   // 128 KB
    const int bid = blockIdx.x;
    if (bid < 192) {
        // QK = x @ [Wq;Wk]^T : M=4096 N=3072 (16 x 12 tiles of 256)
        gemm256_body<1>(x_bf, Wqk, QKb, 3072,
                        (bid / 12) * 256, (bid % 12) * 256, sL);
    } else {
        // Vt = Wv @ x^T : M=1024 N=4096 (4 x 16 tiles of 256)
        int t = bid - 192;
        gemm256_body<1>(Wv, x_bf, Vtb, 4096,
                        (t / 16) * 256, (t % 16) * 256, sL);
    }
}

// ---------------- proven BK=64 128x128 gemm core (for O-proj) --------------
template <int OUT_BF16>
__device__ __forceinline__ void gemm_bt64_body(
        const unsigned short* __restrict__ A,
        const unsigned short* __restrict__ B,
        void* __restrict__ Cp, int K, int ldc, int m0, int n0,
        unsigned short* sA, unsigned short* sB) {
    const int tid  = threadIdx.x;
    const int wave = tid >> 6;
    const int lane = tid & 63;
    const int l16  = lane & 15;
    const int lq   = lane >> 4;
    const int wm   = (wave >> 1) * 64;
    const int wn   = (wave & 1) * 64;

    floatx4 acc[4][4] = {};

    const unsigned short* gA[4];
    const unsigned short* gB[4];
#pragma unroll
    for (int i = 0; i < 4; i++) {
        int c   = wave * 4 + i;
        int row = c * 8 + (lane >> 3);
        int chs = (lane & 7) ^ (row & 7);
        gA[i] = A + (size_t)(m0 + row) * K + chs * 8;
        gB[i] = B + (size_t)(n0 + row) * K + chs * 8;
    }

    for (int k0 = 0; k0 < K; k0 += 64) {
        __syncthreads();
#pragma unroll
        for (int i = 0; i < 4; i++) {
            int c = wave * 4 + i;
            __builtin_amdgcn_global_load_lds(
                (const __attribute__((address_space(1))) void*)gA[i],
                (__attribute__((address_space(3))) void*)(sA + c * 512), 16, 0, 0);
            gA[i] += 64;
            __builtin_amdgcn_global_load_lds(
                (const __attribute__((address_space(1))) void*)gB[i],
                (__attribute__((address_space(3))) void*)(sB + c * 512), 16, 0, 0);
            gB[i] += 64;
        }
        __syncthreads();

        short8 af[2][4], bfr[2][4];
#pragma unroll
        for (int ks = 0; ks < 2; ks++) {
            int slot = (ks * 4 + lq) ^ (l16 & 7);
#pragma unroll
            for (int mb = 0; mb < 4; mb++)
                af[ks][mb] = *(const short8*)(sA + (wm + mb * 16 + l16) * 64 + slot * 8);
#pragma unroll
            for (int nb = 0; nb < 4; nb++)
                bfr[ks][nb] = *(const short8*)(sB + (wn + nb * 16 + l16) * 64 + slot * 8);
        }
#pragma unroll
        for (int ks = 0; ks < 2; ks++)
#pragma unroll
            for (int mb = 0; mb < 4; mb++)
#pragma unroll
                for (int nb = 0; nb < 4; nb++)
                    acc[mb][nb] = __builtin_amdgcn_mfma_f32_16x16x32_bf16(
                        af[ks][mb], bfr[ks][nb], acc[mb][nb], 0, 0, 0);
    }

#pragma unroll
    for (int mb = 0; mb < 4; mb++)
#pragma unroll
        for (int nb = 0; nb < 4; nb++)
#pragma unroll
            for (int r = 0; r < 4; r++) {
                int row = m0 + wm + mb * 16 + lq * 4 + r;
                int col = n0 + wn + nb * 16 + l16;
                if (OUT_BF16)
                    ((unsigned short*)Cp)[(size_t)row * ldc + col] = f2bf(acc[mb][nb][r]);
                else
                    ((float*)Cp)[(size_t)row * ldc + col] = acc[mb][nb][r];
            }
}

// ---------------- O-proj gemm (fp32 out) ----------------
__global__ __launch_bounds__(256) void gemm_o_kernel(
        const unsigned short* __restrict__ A,
        const unsigned short* __restrict__ B,
        float* __restrict__ C) {
    __shared__ __align__(16) unsigned short sA[128 * 64];
    __shared__ __align__(16) unsigned short sB[128 * 64];
    gemm_bt64_body<0>(A, B, C, 2048, 2048,
                      blockIdx.y * 128, blockIdx.x * 128, sA, sB);
}

// ---------------- flash attention v4 (best measured: 100.3 us) -------------
__global__ __launch_bounds__(256, 2) void flash_kernel(
        const unsigned short* __restrict__ QK,
        const unsigned short* __restrict__ Vt,
        unsigned short* __restrict__ O) {
    // layout (ushorts): sK[2][8192] @0, sV[2][8192] @16384, sP[4][2048] @32768
    __shared__ __align__(16) unsigned short smem[40960];

    const int tid  = threadIdx.x;
    const int wave = tid >> 6;
    const int lane = tid & 63;
    const int l16  = lane & 15;
    const int lq   = lane >> 4;
    const int qt   = blockIdx.x;          // 0..15 (128 tokens each)
    const int bh   = blockIdx.y;
    const int b    = bh >> 4;
    const int h    = bh & 15;
    const int kvh  = h >> 1;
    const size_t tokbase = (size_t)b * 2048 + qt * 128 + wave * 32;

    // Q fragments: 32 rows x 128 d per wave (B-operand, col = q = l16)
    short8 qf[2][4];
#pragma unroll
    for (int qb = 0; qb < 2; qb++) {
        const unsigned short* qp =
            QK + (tokbase + qb * 16 + l16) * 3072 + h * 128 + lq * 8;
#pragma unroll
        for (int c = 0; c < 4; c++) qf[qb][c] = *(const short8*)(qp + c * 32);
    }

    const unsigned short* gKe =
        QK + ((size_t)b * 2048 + wave * 16 + lq) * 3072 + 2048 + kvh * 128 +
        (l16 ^ lq) * 8;
    const unsigned short* gKo =
        QK + ((size_t)b * 2048 + wave * 16 + 4 + lq) * 3072 + 2048 + kvh * 128 +
        (l16 ^ (lq + 4)) * 8;
    const unsigned short* gV0 =
        Vt + (size_t)(kvh * 128 + wave * 32 + (lane >> 3)) * 4096 +
        (size_t)b * 2048 + ((lane & 7) ^ (lane >> 3)) * 8;

#define STAGE_KT(sKd, sVd)                                                     \
    do {                                                                       \
        _Pragma("unroll")                                                      \
        for (int i = 0; i < 4; i++) {                                          \
            const unsigned short* gk =                                         \
                ((i & 1) ? gKo : gKe) + (i >> 1) * 24576;                      \
            __builtin_amdgcn_global_load_lds(                                  \
                (const __attribute__((address_space(1))) void*)gk,             \
                (__attribute__((address_space(3))) void*)((sKd) +              \
                                                          (wave * 4 + i) * 512),\
                16, 0, 0);                                                     \
            __builtin_amdgcn_global_load_lds(                                  \
                (const __attribute__((address_space(1))) void*)(gV0 +          \
                                                               i * 32768),     \
                (__attribute__((address_space(3))) void*)((sVd) +              \
                                                          (wave * 4 + i) * 512),\
                16, 0, 0);                                                     \
        }                                                                      \
        gKe += 196608; gKo += 196608; gV0 += 64;                               \
    } while (0)

    unsigned short* pB = smem + 32768 + wave * 2048;

    floatx4 oacc[2][8] = {};
    float l_run[2] = {0.0f, 0.0f};

    STAGE_KT(smem, smem + 16384);
    asm volatile("s_waitcnt vmcnt(0)" ::: "memory");
    __builtin_amdgcn_s_barrier();
    asm volatile("" ::: "memory");

    for (int kt = 0; kt < 32; kt++) {
        const int cur = kt & 1;
        const unsigned short* sKc = smem + cur * 8192;
        const unsigned short* sVc = smem + 16384 + cur * 8192;
        if (kt < 31) {
            unsigned short* sKn = smem + (cur ^ 1) * 8192;
            unsigned short* sVn = smem + 16384 + (cur ^ 1) * 8192;
            STAGE_KT(sKn, sVn);
        }

        // ===== ks0: QK over kb=0,1 + softmax + P write (keys 0..31) =====
#pragma unroll
        for (int kb = 0; kb < 2; kb++) {
            floatx4 sacc[2] = {};
#pragma unroll
            for (int c = 0; c < 4; c++) {
                short8 kf = *(const short8*)(
                    sKc + (kb * 16 + l16) * 128 + (((c * 4 + lq) ^ (l16 & 7)) * 8));
#pragma unroll
                for (int qb = 0; qb < 2; qb++)
                    sacc[qb] = __builtin_amdgcn_mfma_f32_16x16x32_bf16(
                        kf, qf[qb][c], sacc[qb], 0, 0, 0);
            }
#pragma unroll
            for (int qb = 0; qb < 2; qb++) {
                float p0 = __builtin_exp2f(sacc[qb][0]);
                float p1 = __builtin_exp2f(sacc[qb][1]);
                float p2 = __builtin_exp2f(sacc[qb][2]);
                float p3 = __builtin_exp2f(sacc[qb][3]);
                l_run[qb] += (p0 + p1) + (p2 + p3);
                int row = qb * 16 + l16;
                uint2 u;
                u.x = pk_bf16(p0, p1);
                u.y = pk_bf16(p2, p3);
                *(uint2*)(pB + row * 64 +
                          (((kb * 2 + (lq >> 1)) ^ (row & 7)) * 8) +
                          (lq & 1) * 4) = u;
            }
        }
        asm volatile("s_waitcnt lgkmcnt(0)" ::: "memory");

        short8 pf0[2];
#pragma unroll
        for (int qb = 0; qb < 2; qb++) {
            int row = qb * 16 + l16;
            pf0[qb] = *(const short8*)(pB + row * 64 +
                                       ((lq ^ (row & 7)) * 8));
        }

        // ===== PV(ks0) =====
        __builtin_amdgcn_s_setprio(1);
#pragma unroll
        for (int nb = 0; nb < 8; nb++) {
            short8 vf = *(const short8*)(
                sVc + (nb * 16 + l16) * 64 + ((lq ^ (l16 & 7)) * 8));
#pragma unroll
            for (int qb = 0; qb < 2; qb++)
                oacc[qb][nb] = __builtin_amdgcn_mfma_f32_16x16x32_bf16(
                    vf, pf0[qb], oacc[qb][nb], 0, 0, 0);
        }
        __builtin_amdgcn_s_setprio(0);

        // ===== ks1: QK over kb=2,3 + softmax + P write (keys 32..63) =====
#pragma unroll
        for (int kb = 2; kb < 4; kb++) {
            floatx4 sacc[2] = {};
#pragma unroll
            for (int c = 0; c < 4; c++) {
                short8 kf = *(const short8*)(
                    sKc + (kb * 16 + l16) * 128 + (((c * 4 + lq) ^ (l16 & 7)) * 8));
#pragma unroll
                for (int qb = 0; qb < 2; qb++)
                    sacc[qb] = __builtin_amdgcn_mfma_f32_16x16x32_bf16(
                        kf, qf[qb][c], sacc[qb], 0, 0, 0);
            }
#pragma unroll
            for (int qb = 0; qb < 2; qb++) {
                float p0 = __builtin_exp2f(sacc[qb][0]);
                float p1 = __builtin_exp2f(sacc[qb][1]);
                float p2 = __builtin_exp2f(sacc[qb][2]);
                float p3 = __builtin_exp2f(sacc[qb][3]);
                l_run[qb] += (p0 + p1) + (p2 + p3);
                int row = qb * 16 + l16;
                uint2 u;
                u.x = pk_bf16(p0, p1);
                u.y = pk_bf16(p2, p3);
                *(uint2*)(pB + row * 64 +
                          (((kb * 2 + (lq >> 1)) ^ (row & 7)) * 8) +
                          (lq & 1) * 4) = u;
            }
        }
        asm volatile("s_waitcnt lgkmcnt(0)" ::: "memory");

        short8 pf1[2];
#pragma unroll
        for (int qb = 0; qb < 2; qb++) {
            int row = qb * 16 + l16;
            pf1[qb] = *(const short8*)(pB + row * 64 +
                                       (((4 + lq) ^ (row & 7)) * 8));
        }

        // ===== PV(ks1) =====
        __builtin_amdgcn_s_setprio(1);
#pragma unroll
        for (int nb = 0; nb < 8; nb++) {
            short8 vf = *(const short8*)(
                sVc + (nb * 16 + l16) * 64 + (((4 + lq) ^ (l16 & 7)) * 8));
#pragma unroll
            for (int qb = 0; qb < 2; qb++)
                oacc[qb][nb] = __builtin_amdgcn_mfma_f32_16x16x32_bf16(
                    vf, pf1[qb], oacc[qb][nb], 0, 0, 0);
        }
        __builtin_amdgcn_s_setprio(0);

        asm volatile("s_waitcnt vmcnt(0)" ::: "memory");
        __builtin_amdgcn_s_barrier();
        asm volatile("" ::: "memory");
    }
#undef STAGE_KT

#pragma unroll
    for (int qb = 0; qb < 2; qb++) {
        float l = l_run[qb];
        l += __shfl_xor(l, 16);
        l += __shfl_xor(l, 32);
        float inv = 1.0f / l;
        size_t row = (tokbase + qb * 16 + l16) * 2048 + h * 128;
#pragma unroll
        for (int nb = 0; nb < 8; nb++) {
            uint2 u;
            u.x = pk_bf16(oacc[qb][nb][0] * inv, oacc[qb][nb][1] * inv);
            u.y = pk_bf16(oacc[qb][nb][2] * inv, oacc[qb][nb][3] * inv);
            *(uint2*)(O + row + nb * 16 + lq * 4) = u;
        }
    }
}

// ---------------- launcher ----------------
extern "C" void kernel_launch(void* const* d_in, const int* in_sizes, int n_in,
                              void* d_out, int out_size, void* d_ws, size_t ws_size,
                              hipStream_t stream) {
    const float* x  = (const float*)d_in[0];
    const float* Wq = (const float*)d_in[1];
    const float* Wk = (const float*)d_in[2];
    const float* Wv = (const float*)d_in[3];
    const float* Wo = (const float*)d_in[4];

    char* ws = (char*)d_ws;
    unsigned short* x_bf   = (unsigned short*)(ws);               // 16 MB
    unsigned short* Wqk_bf = (unsigned short*)(ws + 16777216);    // 12 MB (Wq;Wk)
    unsigned short* Wv_bf  = (unsigned short*)(ws + 29360128);    // 4 MB
    unsigned short* Wo_bf  = (unsigned short*)(ws + 33554432);    // 8 MB
    unsigned short* QKb    = (unsigned short*)(ws + 41943040);    // 24 MB (4096x3072)
    unsigned short* Vtb    = (unsigned short*)(ws + 67108864);    // 8 MB  (1024x4096)
    unsigned short* Ob     = (unsigned short*)(ws + 75497472);    // 16 MB (4096x2048)

    cast_all_kernel<<<dim3(20480), 256, 0, stream>>>(
        x, Wq, Wk, Wv, Wo, x_bf, Wqk_bf, Wv_bf, Wo_bf);

    // QK = x @ [Wq;Wk]^T  and  Vt = Wv @ x^T (256 blocks = 1/CU, 512 thr)
    gemm_qkv_kernel<<<dim3(256), 512, 0, stream>>>(x_bf, Wqk_bf, Wv_bf, QKb, Vtb);

    // flash attention: 128 tokens/block
    flash_kernel<<<dim3(16, 32), 256, 0, stream>>>(QKb, Vtb, Ob);

    // out = O @ Wo^T : M=4096, N=2048, K=2048, fp32 out (128^2 tiles)
    gemm_o_kernel<<<dim3(16, 32), 256, 0, stream>>>(Ob, Wo_bf, (float*)d_out);
}

// Round 8
// 309.729 us; speedup vs baseline: 1.1942x; 1.0215x over previous
//
#include <hip/hip_runtime.h>
#include <hip/hip_bf16.h>

typedef __attribute__((ext_vector_type(8))) short short8;
typedef __attribute__((ext_vector_type(4))) float floatx4;

__device__ inline unsigned short f2bf(float f) {
    unsigned int u = __float_as_uint(f);
    u += 0x7fffu + ((u >> 16) & 1u);           // round-to-nearest-even
    return (unsigned short)(u >> 16);
}

__device__ inline unsigned int pk_bf16(float lo, float hi) {
    __hip_bfloat162 h = __float22bfloat162_rn(float2{lo, hi});
    unsigned int u;
    __builtin_memcpy(&u, &h, 4);
    return u;
}

// ---------------- merged cast fp32 -> bf16 (all 5 tensors, one launch) -----
// Wq is pre-scaled by scale*log2(e) so flash computes exp2(q.k) directly.
__global__ void cast_all_kernel(const float* __restrict__ x,
                                const float* __restrict__ wq,
                                const float* __restrict__ wk,
                                const float* __restrict__ wv,
                                const float* __restrict__ wo,
                                unsigned short* __restrict__ xb,
                                unsigned short* __restrict__ wqkb,
                                unsigned short* __restrict__ wvb,
                                unsigned short* __restrict__ wob) {
    const float C2 = 0.08838834764831845f * 1.4426950408889634f;
    int bid = blockIdx.x;
    const float* src;
    unsigned short* dst;
    int base;
    float sc = 1.0f;
    if (bid < 8192)       { src = x;  dst = xb;             base = bid; }
    else if (bid < 12288) { src = wq; dst = wqkb;           base = bid - 8192; sc = C2; }
    else if (bid < 14336) { src = wk; dst = wqkb + 4194304; base = bid - 12288; }
    else if (bid < 16384) { src = wv; dst = wvb;            base = bid - 14336; }
    else                  { src = wo; dst = wob;            base = bid - 16384; }
    int i = base * 256 + threadIdx.x;   // float4 units
    float4 v = ((const float4*)src)[i];
    ushort4 o;
    o.x = f2bf(v.x * sc); o.y = f2bf(v.y * sc);
    o.z = f2bf(v.z * sc); o.w = f2bf(v.w * sc);
    ((ushort4*)dst)[i] = o;
}

// ---------------- 256x256 8-phase GEMM, race-hardened pipeline -------------
// (PROVEN r7: passed, qkv ~67us.) Stage runs TWO K-tiles ahead, 4 slots:
// iter t reads slot t&3, stages tile t+2 into slot of tile t-2 (reads
// retired two top-barriers ago). Boundary wait = counted vmcnt(4) (retire
// tile t, keep t+1 in flight). Per tile 2 phases, each {ds_read || stage ->
// barrier -> lgkmcnt(0) -> sched_barrier -> setprio(1) -> 16 MFMA}.
// Chunk = 16 rows x 32 cols (1KB): lane l -> row c*16+(l>>2), lds k-slot l&3
// holds global k-chunk (l&3)^(row&3); frag read slot = lq^(l16&3).
template <int OUT_BF16>
__device__ __forceinline__ void gemm256_body(
        const unsigned short* __restrict__ A,
        const unsigned short* __restrict__ B,
        void* __restrict__ Cp, int ldc, int m0, int n0,
        unsigned short* sL) {
    const int tid  = threadIdx.x;
    const int wave = tid >> 6;
    const int lane = tid & 63;
    const int l16  = lane & 15;
    const int lq   = lane >> 4;
    const int wm   = (wave >> 2) * 128;
    const int wn   = (wave & 3) * 64;
    const int kx   = lq ^ (l16 & 3);

    floatx4 acc[8][4] = {};

    const unsigned short* gA[2];
    const unsigned short* gB[2];
#pragma unroll
    for (int i = 0; i < 2; i++) {
        int c   = wave * 2 + i;
        int row = c * 16 + (lane >> 2);
        int g   = (lane & 3) ^ (row & 3);
        gA[i] = A + (size_t)(m0 + row) * 2048 + g * 8;
        gB[i] = B + (size_t)(n0 + row) * 2048 + g * 8;
    }

#define STG_A32(slot)                                                          \
    do {                                                                       \
        _Pragma("unroll")                                                      \
        for (int i = 0; i < 2; i++) {                                          \
            __builtin_amdgcn_global_load_lds(                                  \
                (const __attribute__((address_space(1))) void*)gA[i],          \
                (__attribute__((address_space(3))) void*)(sL + (slot) * 16384 +\
                                                          (wave * 2 + i) * 512),\
                16, 0, 0);                                                     \
            gA[i] += 32;                                                       \
        }                                                                      \
    } while (0)
#define STG_B32(slot)                                                          \
    do {                                                                       \
        _Pragma("unroll")                                                      \
        for (int i = 0; i < 2; i++) {                                          \
            __builtin_amdgcn_global_load_lds(                                  \
                (const __attribute__((address_space(1))) void*)gB[i],          \
                (__attribute__((address_space(3))) void*)(sL + (slot) * 16384 +\
                                                  8192 + (wave * 2 + i) * 512),\
                16, 0, 0);                                                     \
            gB[i] += 32;                                                       \
        }                                                                      \
    } while (0)

    // prologue: stage tiles 0,1 into slots 0,1 (8 loads/wave in flight)
    STG_A32(0); STG_B32(0);
    STG_A32(1); STG_B32(1);

    for (int t = 0; t < 64; t++) {
        const int sc = t & 3;
        const int sn = (t + 2) & 3;        // slot of tile t-2 (retired reads)
        // boundary: retire tile t's 4 loads; tile t+1 stays in flight
        if (t < 63) asm volatile("s_waitcnt vmcnt(4)" ::: "memory");
        else        asm volatile("s_waitcnt vmcnt(0)" ::: "memory");
        __builtin_amdgcn_s_barrier();
        asm volatile("" ::: "memory");

        const unsigned short* sAc = sL + sc * 16384;
        const unsigned short* sBc = sAc + 8192;
        short8 af[4], bf[4];

        // ---- phase 0: mh0 (mb 0-3) ----
#pragma unroll
        for (int mb = 0; mb < 4; mb++)
            af[mb] = *(const short8*)(sAc + (wm + mb * 16 + l16) * 32 + kx * 8);
#pragma unroll
        for (int nb = 0; nb < 4; nb++)
            bf[nb] = *(const short8*)(sBc + (wn + nb * 16 + l16) * 32 + kx * 8);
        if (t < 62) STG_A32(sn);
        __builtin_amdgcn_s_barrier();
        asm volatile("s_waitcnt lgkmcnt(0)" ::: "memory");
        __builtin_amdgcn_sched_barrier(0);
        __builtin_amdgcn_s_setprio(1);
#pragma unroll
        for (int mb = 0; mb < 4; mb++)
#pragma unroll
            for (int nb = 0; nb < 4; nb++)
                acc[mb][nb] = __builtin_amdgcn_mfma_f32_16x16x32_bf16(
                    af[mb], bf[nb], acc[mb][nb], 0, 0, 0);
        __builtin_amdgcn_s_setprio(0);
        __builtin_amdgcn_s_barrier();
        asm volatile("" ::: "memory");

        // ---- phase 1: mh1 (mb 4-7), bf reused from registers ----
#pragma unroll
        for (int mb = 0; mb < 4; mb++)
            af[mb] = *(const short8*)(sAc + (wm + 64 + mb * 16 + l16) * 32 + kx * 8);
        if (t < 62) STG_B32(sn);
        __builtin_amdgcn_s_barrier();
        asm volatile("s_waitcnt lgkmcnt(0)" ::: "memory");
        __builtin_amdgcn_sched_barrier(0);
        __builtin_amdgcn_s_setprio(1);
#pragma unroll
        for (int mb = 0; mb < 4; mb++)
#pragma unroll
            for (int nb = 0; nb < 4; nb++)
                acc[4 + mb][nb] = __builtin_amdgcn_mfma_f32_16x16x32_bf16(
                    af[mb], bf[nb], acc[4 + mb][nb], 0, 0, 0);
        __builtin_amdgcn_s_setprio(0);
        // tile closed by next iteration's vmcnt + barrier
    }
#undef STG_A32
#undef STG_B32

#pragma unroll
    for (int mb = 0; mb < 8; mb++)
#pragma unroll
        for (int nb = 0; nb < 4; nb++)
#pragma unroll
            for (int r = 0; r < 4; r++) {
                int row = m0 + wm + mb * 16 + lq * 4 + r;
                int col = n0 + wn + nb * 16 + l16;
                if (OUT_BF16)
                    ((unsigned short*)Cp)[(size_t)row * ldc + col] = f2bf(acc[mb][nb][r]);
                else
                    ((float*)Cp)[(size_t)row * ldc + col] = acc[mb][nb][r];
            }
}

// ---------------- 128x256 single-phase variant (same hardened pipeline) ----
// For gemm_o: M=4096 N=2048 -> 32x8 = 256 blocks (1/CU; a 256^2 tile would
// give only 128 blocks = half the GPU idle). 8 waves 2Mx4N, wave-out 64x64,
// acc[4][4]; one phase/tile {8 ds_read || 3 gload_lds -> barrier -> lgkm ->
// 16 MFMA}. Slots 24KB x 4 = 96KB; stage 2 ahead into slot of tile t-2;
// counted vmcnt(3) keeps tile t+1's 3 loads in flight. Chunk/swizzle
// formulas identical to gemm256_body (proven).
template <int OUT_BF16>
__device__ __forceinline__ void gemm128_body(
        const unsigned short* __restrict__ A,
        const unsigned short* __restrict__ B,
        void* __restrict__ Cp, int ldc, int m0, int n0,
        unsigned short* sL) {
    const int tid  = threadIdx.x;
    const int wave = tid >> 6;
    const int lane = tid & 63;
    const int l16  = lane & 15;
    const int lq   = lane >> 4;
    const int wm   = (wave >> 2) * 64;
    const int wn   = (wave & 3) * 64;
    const int kx   = lq ^ (l16 & 3);

    floatx4 acc[4][4] = {};

    const unsigned short* gA0;
    const unsigned short* gB[2];
    {
        int row = wave * 16 + (lane >> 2);              // A chunk = wave
        int g   = (lane & 3) ^ (row & 3);
        gA0 = A + (size_t)(m0 + row) * 2048 + g * 8;
    }
#pragma unroll
    for (int i = 0; i < 2; i++) {
        int c   = wave * 2 + i;                         // B chunks
        int row = c * 16 + (lane >> 2);
        int g   = (lane & 3) ^ (row & 3);
        gB[i] = B + (size_t)(n0 + row) * 2048 + g * 8;
    }

#define STG_O(slot)                                                            \
    do {                                                                       \
        __builtin_amdgcn_global_load_lds(                                      \
            (const __attribute__((address_space(1))) void*)gA0,                \
            (__attribute__((address_space(3))) void*)(sL + (slot) * 12288 +    \
                                                      wave * 512),             \
            16, 0, 0);                                                         \
        gA0 += 32;                                                             \
        _Pragma("unroll")                                                      \
        for (int i = 0; i < 2; i++) {                                          \
            __builtin_amdgcn_global_load_lds(                                  \
                (const __attribute__((address_space(1))) void*)gB[i],          \
                (__attribute__((address_space(3))) void*)(sL + (slot) * 12288 +\
                                                  4096 + (wave * 2 + i) * 512),\
                16, 0, 0);                                                     \
            gB[i] += 32;                                                       \
        }                                                                      \
    } while (0)

    // prologue: stage tiles 0,1 into slots 0,1 (6 loads/wave in flight)
    STG_O(0); STG_O(1);

    for (int t = 0; t < 64; t++) {
        const int sc = t & 3;
        const int sn = (t + 2) & 3;        // slot of tile t-2 (retired reads)
        if (t < 63) asm volatile("s_waitcnt vmcnt(3)" ::: "memory");
        else        asm volatile("s_waitcnt vmcnt(0)" ::: "memory");
        __builtin_amdgcn_s_barrier();
        asm volatile("" ::: "memory");

        const unsigned short* sAc = sL + sc * 12288;
        const unsigned short* sBc = sAc + 4096;
        short8 af[4], bf[4];
#pragma unroll
        for (int mb = 0; mb < 4; mb++)
            af[mb] = *(const short8*)(sAc + (wm + mb * 16 + l16) * 32 + kx * 8);
#pragma unroll
        for (int nb = 0; nb < 4; nb++)
            bf[nb] = *(const short8*)(sBc + (wn + nb * 16 + l16) * 32 + kx * 8);
        if (t < 62) STG_O(sn);
        __builtin_amdgcn_s_barrier();
        asm volatile("s_waitcnt lgkmcnt(0)" ::: "memory");
        __builtin_amdgcn_sched_barrier(0);
        __builtin_amdgcn_s_setprio(1);
#pragma unroll
        for (int mb = 0; mb < 4; mb++)
#pragma unroll
            for (int nb = 0; nb < 4; nb++)
                acc[mb][nb] = __builtin_amdgcn_mfma_f32_16x16x32_bf16(
                    af[mb], bf[nb], acc[mb][nb], 0, 0, 0);
        __builtin_amdgcn_s_setprio(0);
        // tile closed by next iteration's vmcnt + barrier
    }
#undef STG_O

#pragma unroll
    for (int mb = 0; mb < 4; mb++)
#pragma unroll
        for (int nb = 0; nb < 4; nb++)
#pragma unroll
            for (int r = 0; r < 4; r++) {
                int row = m0 + wm + mb * 16 + lq * 4 + r;
                int col = n0 + wn + nb * 16 + l16;
                if (OUT_BF16)
                    ((unsigned short*)Cp)[(size_t)row * ldc + col] = f2bf(acc[mb][nb][r]);
                else
                    ((float*)Cp)[(size_t)row * ldc + col] = acc[mb][nb][r];
            }
}

// ---------------- merged QK + Vt gemm (256 blocks = 1/CU) ------------------
__global__ __launch_bounds__(512, 1) void gemm_qkv_kernel(
        const unsigned short* __restrict__ x_bf,
        const unsigned short* __restrict__ Wqk,
        const unsigned short* __restrict__ Wv,
        unsigned short* __restrict__ QKb,
        unsigned short* __restrict__ Vtb) {
    __shared__ __align__(16) unsigned short sL[4 * 16384];   // 128 KB
    const int bid = blockIdx.x;
    if (bid < 192) {
        // QK = x @ [Wq;Wk]^T : M=4096 N=3072 (16 x 12 tiles of 256)
        gemm256_body<1>(x_bf, Wqk, QKb, 3072,
                        (bid / 12) * 256, (bid % 12) * 256, sL);
    } else {
        // Vt = Wv @ x^T : M=1024 N=4096 (4 x 16 tiles of 256)
        int t = bid - 192;
        gemm256_body<1>(Wv, x_bf, Vtb, 4096,
                        (t / 16) * 256, (t % 16) * 256, sL);
    }
}

// ---------------- O-proj gemm (fp32 out, 256 blocks = 1/CU) ----------------
__global__ __launch_bounds__(512, 1) void gemm_o_kernel(
        const unsigned short* __restrict__ A,
        const unsigned short* __restrict__ B,
        float* __restrict__ C) {
    __shared__ __align__(16) unsigned short sL[4 * 12288];   // 96 KB
    gemm128_body<0>(A, B, C, 2048,
                    blockIdx.y * 128, blockIdx.x * 256, sL);
}

// ---------------- flash attention v4 (best measured: 98.9 us) --------------
__global__ __launch_bounds__(256, 2) void flash_kernel(
        const unsigned short* __restrict__ QK,
        const unsigned short* __restrict__ Vt,
        unsigned short* __restrict__ O) {
    // layout (ushorts): sK[2][8192] @0, sV[2][8192] @16384, sP[4][2048] @32768
    __shared__ __align__(16) unsigned short smem[40960];

    const int tid  = threadIdx.x;
    const int wave = tid >> 6;
    const int lane = tid & 63;
    const int l16  = lane & 15;
    const int lq   = lane >> 4;
    const int qt   = blockIdx.x;          // 0..15 (128 tokens each)
    const int bh   = blockIdx.y;
    const int b    = bh >> 4;
    const int h    = bh & 15;
    const int kvh  = h >> 1;
    const size_t tokbase = (size_t)b * 2048 + qt * 128 + wave * 32;

    // Q fragments: 32 rows x 128 d per wave (B-operand, col = q = l16)
    short8 qf[2][4];
#pragma unroll
    for (int qb = 0; qb < 2; qb++) {
        const unsigned short* qp =
            QK + (tokbase + qb * 16 + l16) * 3072 + h * 128 + lq * 8;
#pragma unroll
        for (int c = 0; c < 4; c++) qf[qb][c] = *(const short8*)(qp + c * 32);
    }

    const unsigned short* gKe =
        QK + ((size_t)b * 2048 + wave * 16 + lq) * 3072 + 2048 + kvh * 128 +
        (l16 ^ lq) * 8;
    const unsigned short* gKo =
        QK + ((size_t)b * 2048 + wave * 16 + 4 + lq) * 3072 + 2048 + kvh * 128 +
        (l16 ^ (lq + 4)) * 8;
    const unsigned short* gV0 =
        Vt + (size_t)(kvh * 128 + wave * 32 + (lane >> 3)) * 4096 +
        (size_t)b * 2048 + ((lane & 7) ^ (lane >> 3)) * 8;

#define STAGE_KT(sKd, sVd)                                                     \
    do {                                                                       \
        _Pragma("unroll")                                                      \
        for (int i = 0; i < 4; i++) {                                          \
            const unsigned short* gk =                                         \
                ((i & 1) ? gKo : gKe) + (i >> 1) * 24576;                      \
            __builtin_amdgcn_global_load_lds(                                  \
                (const __attribute__((address_space(1))) void*)gk,             \
                (__attribute__((address_space(3))) void*)((sKd) +              \
                                                          (wave * 4 + i) * 512),\
                16, 0, 0);                                                     \
            __builtin_amdgcn_global_load_lds(                                  \
                (const __attribute__((address_space(1))) void*)(gV0 +          \
                                                               i * 32768),     \
                (__attribute__((address_space(3))) void*)((sVd) +              \
                                                          (wave * 4 + i) * 512),\
                16, 0, 0);                                                     \
        }                                                                      \
        gKe += 196608; gKo += 196608; gV0 += 64;                               \
    } while (0)

    unsigned short* pB = smem + 32768 + wave * 2048;

    floatx4 oacc[2][8] = {};
    float l_run[2] = {0.0f, 0.0f};

    STAGE_KT(smem, smem + 16384);
    asm volatile("s_waitcnt vmcnt(0)" ::: "memory");
    __builtin_amdgcn_s_barrier();
    asm volatile("" ::: "memory");

    for (int kt = 0; kt < 32; kt++) {
        const int cur = kt & 1;
        const unsigned short* sKc = smem + cur * 8192;
        const unsigned short* sVc = smem + 16384 + cur * 8192;
        if (kt < 31) {
            unsigned short* sKn = smem + (cur ^ 1) * 8192;
            unsigned short* sVn = smem + 16384 + (cur ^ 1) * 8192;
            STAGE_KT(sKn, sVn);
        }

        // ===== ks0: QK over kb=0,1 + softmax + P write (keys 0..31) =====
#pragma unroll
        for (int kb = 0; kb < 2; kb++) {
            floatx4 sacc[2] = {};
#pragma unroll
            for (int c = 0; c < 4; c++) {
                short8 kf = *(const short8*)(
                    sKc + (kb * 16 + l16) * 128 + (((c * 4 + lq) ^ (l16 & 7)) * 8));
#pragma unroll
                for (int qb = 0; qb < 2; qb++)
                    sacc[qb] = __builtin_amdgcn_mfma_f32_16x16x32_bf16(
                        kf, qf[qb][c], sacc[qb], 0, 0, 0);
            }
#pragma unroll
            for (int qb = 0; qb < 2; qb++) {
                float p0 = __builtin_exp2f(sacc[qb][0]);
                float p1 = __builtin_exp2f(sacc[qb][1]);
                float p2 = __builtin_exp2f(sacc[qb][2]);
                float p3 = __builtin_exp2f(sacc[qb][3]);
                l_run[qb] += (p0 + p1) + (p2 + p3);
                int row = qb * 16 + l16;
                uint2 u;
                u.x = pk_bf16(p0, p1);
                u.y = pk_bf16(p2, p3);
                *(uint2*)(pB + row * 64 +
                          (((kb * 2 + (lq >> 1)) ^ (row & 7)) * 8) +
                          (lq & 1) * 4) = u;
            }
        }
        asm volatile("s_waitcnt lgkmcnt(0)" ::: "memory");

        short8 pf0[2];
#pragma unroll
        for (int qb = 0; qb < 2; qb++) {
            int row = qb * 16 + l16;
            pf0[qb] = *(const short8*)(pB + row * 64 +
                                       ((lq ^ (row & 7)) * 8));
        }

        // ===== PV(ks0) =====
        __builtin_amdgcn_s_setprio(1);
#pragma unroll
        for (int nb = 0; nb < 8; nb++) {
            short8 vf = *(const short8*)(
                sVc + (nb * 16 + l16) * 64 + ((lq ^ (l16 & 7)) * 8));
#pragma unroll
            for (int qb = 0; qb < 2; qb++)
                oacc[qb][nb] = __builtin_amdgcn_mfma_f32_16x16x32_bf16(
                    vf, pf0[qb], oacc[qb][nb], 0, 0, 0);
        }
        __builtin_amdgcn_s_setprio(0);

        // ===== ks1: QK over kb=2,3 + softmax + P write (keys 32..63) =====
#pragma unroll
        for (int kb = 2; kb < 4; kb++) {
            floatx4 sacc[2] = {};
#pragma unroll
            for (int c = 0; c < 4; c++) {
                short8 kf = *(const short8*)(
                    sKc + (kb * 16 + l16) * 128 + (((c * 4 + lq) ^ (l16 & 7)) * 8));
#pragma unroll
                for (int qb = 0; qb < 2; qb++)
                    sacc[qb] = __builtin_amdgcn_mfma_f32_16x16x32_bf16(
                        kf, qf[qb][c], sacc[qb], 0, 0, 0);
            }
#pragma unroll
            for (int qb = 0; qb < 2; qb++) {
                float p0 = __builtin_exp2f(sacc[qb][0]);
                float p1 = __builtin_exp2f(sacc[qb][1]);
                float p2 = __builtin_exp2f(sacc[qb][2]);
                float p3 = __builtin_exp2f(sacc[qb][3]);
                l_run[qb] += (p0 + p1) + (p2 + p3);
                int row = qb * 16 + l16;
                uint2 u;
                u.x = pk_bf16(p0, p1);
                u.y = pk_bf16(p2, p3);
                *(uint2*)(pB + row * 64 +
                          (((kb * 2 + (lq >> 1)) ^ (row & 7)) * 8) +
                          (lq & 1) * 4) = u;
            }
        }
        asm volatile("s_waitcnt lgkmcnt(0)" ::: "memory");

        short8 pf1[2];
#pragma unroll
        for (int qb = 0; qb < 2; qb++) {
            int row = qb * 16 + l16;
            pf1[qb] = *(const short8*)(pB + row * 64 +
                                       (((4 + lq) ^ (row & 7)) * 8));
        }

        // ===== PV(ks1) =====
        __builtin_amdgcn_s_setprio(1);
#pragma unroll
        for (int nb = 0; nb < 8; nb++) {
            short8 vf = *(const short8*)(
                sVc + (nb * 16 + l16) * 64 + (((4 + lq) ^ (l16 & 7)) * 8));
#pragma unroll
            for (int qb = 0; qb < 2; qb++)
                oacc[qb][nb] = __builtin_amdgcn_mfma_f32_16x16x32_bf16(
                    vf, pf1[qb], oacc[qb][nb], 0, 0, 0);
        }
        __builtin_amdgcn_s_setprio(0);

        asm volatile("s_waitcnt vmcnt(0)" ::: "memory");
        __builtin_amdgcn_s_barrier();
        asm volatile("" ::: "memory");
    }
#undef STAGE_KT

#pragma unroll
    for (int qb = 0; qb < 2; qb++) {
        float l = l_run[qb];
        l += __shfl_xor(l, 16);
        l += __shfl_xor(l, 32);
        float inv = 1.0f / l;
        size_t row = (tokbase + qb * 16 + l16) * 2048 + h * 128;
#pragma unroll
        for (int nb = 0; nb < 8; nb++) {
            uint2 u;
            u.x = pk_bf16(oacc[qb][nb][0] * inv, oacc[qb][nb][1] * inv);
            u.y = pk_bf16(oacc[qb][nb][2] * inv, oacc[qb][nb][3] * inv);
            *(uint2*)(O + row + nb * 16 + lq * 4) = u;
        }
    }
}

// ---------------- launcher ----------------
extern "C" void kernel_launch(void* const* d_in, const int* in_sizes, int n_in,
                              void* d_out, int out_size, void* d_ws, size_t ws_size,
                              hipStream_t stream) {
    const float* x  = (const float*)d_in[0];
    const float* Wq = (const float*)d_in[1];
    const float* Wk = (const float*)d_in[2];
    const float* Wv = (const float*)d_in[3];
    const float* Wo = (const float*)d_in[4];

    char* ws = (char*)d_ws;
    unsigned short* x_bf   = (unsigned short*)(ws);               // 16 MB
    unsigned short* Wqk_bf = (unsigned short*)(ws + 16777216);    // 12 MB (Wq;Wk)
    unsigned short* Wv_bf  = (unsigned short*)(ws + 29360128);    // 4 MB
    unsigned short* Wo_bf  = (unsigned short*)(ws + 33554432);    // 8 MB
    unsigned short* QKb    = (unsigned short*)(ws + 41943040);    // 24 MB (4096x3072)
    unsigned short* Vtb    = (unsigned short*)(ws + 67108864);    // 8 MB  (1024x4096)
    unsigned short* Ob     = (unsigned short*)(ws + 75497472);    // 16 MB (4096x2048)

    cast_all_kernel<<<dim3(20480), 256, 0, stream>>>(
        x, Wq, Wk, Wv, Wo, x_bf, Wqk_bf, Wv_bf, Wo_bf);

    // QK = x @ [Wq;Wk]^T  and  Vt = Wv @ x^T (256 blocks = 1/CU, 512 thr)
    gemm_qkv_kernel<<<dim3(256), 512, 0, stream>>>(x_bf, Wqk_bf, Wv_bf, QKb, Vtb);

    // flash attention: 128 tokens/block
    flash_kernel<<<dim3(16, 32), 256, 0, stream>>>(QKb, Vtb, Ob);

    // out = O @ Wo^T : M=4096, N=2048, K=2048, fp32 out (32 x 8 tiles)
    gemm_o_kernel<<<dim3(8, 32), 512, 0, stream>>>(Ob, Wo_bf, (float*)d_out);
}